// Round 4
// baseline (3447.797 us; speedup 1.0000x reference)
//
#include <hip/hip_runtime.h>

typedef unsigned short u16;
typedef unsigned int u32;

struct __align__(8) us4 { u16 x, y, z, w; };

__device__ __forceinline__ float bf1(u16 v){ return __uint_as_float(((u32)v) << 16); }
__device__ __forceinline__ float bflo(u32 u){ return __uint_as_float(u << 16); }
__device__ __forceinline__ float bfhi(u32 u){ return __uint_as_float(u & 0xFFFF0000u); }
__device__ __forceinline__ u16 fbf(float f){
    u32 u = __float_as_uint(f);
    return (u16)((u + 0x7FFFu + ((u >> 16) & 1u)) >> 16);   // RTNE
}
__device__ __forceinline__ float gelu_exact(float x){
    return 0.5f * x * (1.0f + erff(x * 0.70710678118654752f));
}
__device__ __forceinline__ void unp8(uint4 u, float* f){
    f[0]=bflo(u.x); f[1]=bfhi(u.x); f[2]=bflo(u.y); f[3]=bfhi(u.y);
    f[4]=bflo(u.z); f[5]=bfhi(u.z); f[6]=bflo(u.w); f[7]=bfhi(u.w);
}
__device__ __forceinline__ uint4 pack8(float4 a, float4 b){
    uint4 u;
    u.x = (u32)fbf(a.x) | ((u32)fbf(a.y) << 16);
    u.y = (u32)fbf(a.z) | ((u32)fbf(a.w) << 16);
    u.z = (u32)fbf(b.x) | ((u32)fbf(b.y) << 16);
    u.w = (u32)fbf(b.z) | ((u32)fbf(b.w) << 16);
    return u;
}

#define S_SEC 23

// LDS regions inside SM[61184] (bytes):
//  [0,11776)     : redp u16[23][256]   (LN -> end; sec overlays before)
//  [11776,35328) : R1: h2 f32[23][256] -> q,k u16 -> ctx f32
//  [35328,52992) : R2: h1 u16[23][384] -> attn f32[8*23*23]
//  [52992,61184) : wt: swizzled 64x64 bf16 weight tile (GEMM phases only)
//  sec u16[23][768] = 35328 B overlays [0,35328) during GEMM1 only.

// out[s][m] = gelu(sum_k SRC[s][k]*W[m][k] + bias[m]); SRC: LDS bf16.
// W, bias: global fp32 (converted to bf16 in the LDS tile).
__device__ void gemm_stage(const u16* __restrict__ SRC, int srcStride, int K,
                           const float* __restrict__ W, const float* __restrict__ bias,
                           int Mtiles, u16* wtp,
                           u16* out16, float* out32, int outStride, int t)
{
    const int ml = t & 31, sg = t >> 5;
    const int nS = (sg < 7) ? 3 : 2;          // s = sg, sg+8, sg+16 (<23)
    const int kT = K >> 6;
    for (int mb = 0; mb < Mtiles; ++mb) {
        float acc[3][2] = {{0.f,0.f},{0.f,0.f},{0.f,0.f}};
        for (int kb = 0; kb < kT; ++kb) {
            __syncthreads();                   // prior compute done before tile overwrite
            #pragma unroll
            for (int i = 0; i < 2; ++i) {      // 64x64 fp32 tile -> bf16 LDS, 512 chunks of 8
                const int idx = t + 256*i;
                const int r = idx >> 3, j = idx & 7;
                const float* src = W + (size_t)(mb*64 + r)*K + kb*64 + j*8;
                float4 f0 = *(const float4*)src;
                float4 f1 = *(const float4*)(src + 4);
                *(uint4*)(wtp + r*64 + ((j ^ (r & 7)) * 8)) = pack8(f0, f1);
            }
            __syncthreads();
            #pragma unroll
            for (int j8 = 0; j8 < 8; ++j8) {
                float wa[8], wb[8];
                unp8(*(const uint4*)(wtp + ml*64       + ((j8 ^ (ml & 7)) * 8)), wa);
                unp8(*(const uint4*)(wtp + (ml+32)*64  + ((j8 ^ (ml & 7)) * 8)), wb);
                #pragma unroll
                for (int si = 0; si < 3; ++si) {
                    if (si < nS) {
                        const int s = sg + si*8;
                        float af[8];
                        unp8(*(const uint4*)(SRC + s*srcStride + kb*64 + j8*8), af);
                        float a0 = 0.f, a1 = 0.f;
                        #pragma unroll
                        for (int e = 0; e < 8; ++e){ a0 += af[e]*wa[e]; a1 += af[e]*wb[e]; }
                        acc[si][0] += a0; acc[si][1] += a1;
                    }
                }
            }
        }
        const int m0 = mb*64 + ml, m1 = m0 + 32;
        const float ba = bias[m0], bb = bias[m1];
        #pragma unroll
        for (int si = 0; si < 3; ++si) {
            if (si < nS) {
                const int s = sg + si*8;
                const float v0 = gelu_exact(acc[si][0] + ba);
                const float v1 = gelu_exact(acc[si][1] + bb);
                if (out16) { out16[s*outStride + m0] = fbf(v0); out16[s*outStride + m1] = fbf(v1); }
                else       { out32[s*outStride + m0] = v0;      out32[s*outStride + m1] = v1; }
            }
        }
    }
}

// acc[s] = bias[t] + sum_c red[s][c] * W[t][c]; W global fp32, red LDS bf16.
__device__ __forceinline__ void projcol(const u16* redp, const float* __restrict__ W,
                                        const float* __restrict__ bias, int t, float* acc)
{
    const float b0 = bias[t];
    #pragma unroll
    for (int s = 0; s < S_SEC; ++s) acc[s] = b0;
    for (int c8 = 0; c8 < 32; ++c8) {
        const float* wp = W + (size_t)t*256 + c8*8;
        float wf[8];
        { float4 w0 = *(const float4*)wp, w1 = *(const float4*)(wp + 4);
          wf[0]=w0.x; wf[1]=w0.y; wf[2]=w0.z; wf[3]=w0.w;
          wf[4]=w1.x; wf[5]=w1.y; wf[6]=w1.z; wf[7]=w1.w; }
        #pragma unroll
        for (int s = 0; s < S_SEC; ++s) {
            float rf[8];
            unp8(*(const uint4*)(redp + s*256 + c8*8), rf);   // wave-uniform -> broadcast
            float a = 0.f;
            #pragma unroll
            for (int e = 0; e < 8; ++e) a += rf[e]*wf[e];
            acc[s] += a;
        }
    }
}

__global__ __launch_bounds__(256) void mega_kernel(
    const float* __restrict__ cls, const int* __restrict__ mask,
    const float* __restrict__ missing,
    const float* __restrict__ W1, const float* __restrict__ b1,
    const float* __restrict__ W2, const float* __restrict__ b2,
    const float* __restrict__ lng, const float* __restrict__ lnb,
    const float* __restrict__ Wq, const float* __restrict__ bq,
    const float* __restrict__ Wk, const float* __restrict__ bk,
    const float* __restrict__ Wv, const float* __restrict__ bv,
    const float* __restrict__ Wo, const float* __restrict__ bo,
    const float* __restrict__ Wp, const float* __restrict__ bp,
    float* __restrict__ out, float* __restrict__ lossAcc)
{
    __shared__ __align__(16) unsigned char SM[61184];
    __shared__ int   sEx[S_SEC];
    __shared__ float sInv[S_SEC];
    __shared__ float sPool[256];
    __shared__ float sRsc[4];

    const int b = blockIdx.x, t = threadIdx.x;

    u16*   redp  = (u16*)SM;
    u16*   secp  = (u16*)SM;                       // GEMM1-phase overlay
    float* h2p   = (float*)(SM + 11776);
    u16*   qp    = (u16*)(SM + 11776);
    u16*   kp    = (u16*)(SM + 23552);
    float* ctxp  = (float*)(SM + 11776);
    u16*   h1p   = (u16*)(SM + 35328);
    float* attnp = (float*)(SM + 35328);
    u16*   wtp   = (u16*)(SM + 52992);

    if (t < S_SEC) sEx[t] = mask[b*S_SEC + t];
    __syncthreads();

    // ---- gather sec (23x768 fp32 -> bf16 LDS) ----
    for (int idx = t; idx < 4416; idx += 256) {            // 4416 = 23*192 float4
        const int s = idx / 192, c4 = (idx - s*192) * 4;
        const float* src = (sEx[s] > 0) ? (cls + ((size_t)(b*S_SEC + s))*768 + c4)
                                        : (missing + (size_t)s*768 + c4);
        float4 f = *(const float4*)src;
        us4 o; o.x = fbf(f.x); o.y = fbf(f.y); o.z = fbf(f.z); o.w = fbf(f.w);
        *(us4*)(secp + s*768 + c4) = o;
    }
    __syncthreads();

    // ---- h1 = gelu(sec @ W1^T + b1) -> h1p (bf16, stride 384) ----
    gemm_stage(secp, 768, 768, W1, b1, 6, wtp, h1p, nullptr, 384, t);
    __syncthreads();

    // ---- h2 = gelu(h1 @ W2^T + b2) -> h2p (fp32, stride 256) ----
    gemm_stage(h1p, 384, 384, W2, b2, 4, wtp, nullptr, h2p, 256, t);
    __syncthreads();

    // ---- red = LN(h2) -> redp (bf16). One wave per row group. ----
    {
        const int w = t >> 6, l = t & 63;
        float gg[4], bbv[4];
        #pragma unroll
        for (int i = 0; i < 4; ++i){ gg[i] = lng[l*4 + i]; bbv[i] = lnb[l*4 + i]; }
        for (int r = w; r < S_SEC; r += 4) {
            const float4 x = *((const float4*)h2p + r*64 + l);
            float sum = x.x + x.y + x.z + x.w;
            #pragma unroll
            for (int m = 32; m; m >>= 1) sum += __shfl_xor(sum, m);
            const float mu = sum * (1.f/256.f);
            const float d0 = x.x-mu, d1 = x.y-mu, d2 = x.z-mu, d3 = x.w-mu;
            float vs = d0*d0 + d1*d1 + d2*d2 + d3*d3;
            #pragma unroll
            for (int m = 32; m; m >>= 1) vs += __shfl_xor(vs, m);
            const float rs = rsqrtf(vs * (1.f/256.f) + 1e-5f);
            us4 o;
            o.x = fbf(d0*rs*gg[0] + bbv[0]);
            o.y = fbf(d1*rs*gg[1] + bbv[1]);
            o.z = fbf(d2*rs*gg[2] + bbv[2]);
            o.w = fbf(d3*rs*gg[3] + bbv[3]);
            *((us4*)redp + r*64 + l) = o;
        }
    }
    __syncthreads();

    // ---- q,k -> LDS bf16; v -> registers (thread t owns column d=t) ----
    float vreg[S_SEC];
    {
        float acc[S_SEC];
        projcol(redp, Wq, bq, t, acc);
        #pragma unroll
        for (int s = 0; s < S_SEC; ++s) qp[s*256 + t] = fbf(acc[s]);
        projcol(redp, Wk, bk, t, acc);
        #pragma unroll
        for (int s = 0; s < S_SEC; ++s) kp[s*256 + t] = fbf(acc[s]);
        projcol(redp, Wv, bv, t, vreg);
    }
    __syncthreads();

    // ---- masked softmax scores -> attnp ----
    {
        float p[S_SEC];
        float inv_sum = 0.f;
        const int hh = t / S_SEC, qi = t - hh*S_SEC;
        if (t < 8*S_SEC) {
            const u16* qrow = qp + qi*256 + hh*32;
            float mx = -1e30f;
            #pragma unroll
            for (int j = 0; j < S_SEC; ++j) {
                const u16* krow = kp + j*256 + hh*32;
                float sc = 0.f;
                #pragma unroll
                for (int d8 = 0; d8 < 4; ++d8) {
                    float qa[8], ka[8];
                    unp8(*(const uint4*)(qrow + d8*8), qa);
                    unp8(*(const uint4*)(krow + d8*8), ka);
                    #pragma unroll
                    for (int e = 0; e < 8; ++e) sc += qa[e]*ka[e];
                }
                sc *= 0.17677669529663687f;        // 1/sqrt(32)
                if (sEx[j] <= 0) sc = -1e9f;
                p[j] = sc; mx = fmaxf(mx, sc);
            }
            float sum = 0.f;
            #pragma unroll
            for (int j = 0; j < S_SEC; ++j){ p[j] = expf(p[j] - mx); sum += p[j]; }
            inv_sum = 1.f / sum;
        }
        __syncthreads();                            // q/k reads done before R1 reuse
        if (t < 8*S_SEC) {
            #pragma unroll
            for (int j = 0; j < S_SEC; ++j)
                attnp[(hh*S_SEC + qi)*S_SEC + j] = p[j] * inv_sum;
        }
    }
    __syncthreads();

    // ---- ctx[s][t] = sum_j attn[h][s][j] * v[j][t]  (h = t>>5) ----
    {
        const int h = t >> 5;
        #pragma unroll
        for (int s = 0; s < S_SEC; ++s) {
            float a = 0.f;
            #pragma unroll
            for (int j = 0; j < S_SEC; ++j) a += attnp[(h*S_SEC + s)*S_SEC + j] * vreg[j];
            ctxp[s*256 + t] = a;
        }
    }
    __syncthreads();

    // ---- mha_out = ctx @ Wo^T + bo, scattered into missing rows of red ----
    {
        bool any = false;
        #pragma unroll
        for (int s = 0; s < S_SEC; ++s) any = any || (sEx[s] > 0);
        u32 updm = 0;
        #pragma unroll
        for (int s = 0; s < S_SEC; ++s) if (any && sEx[s] <= 0) updm |= (1u << s);
        if (updm) {
            float macc[S_SEC];
            const float b0 = bo[t];
            #pragma unroll
            for (int s = 0; s < S_SEC; ++s) macc[s] = b0;
            for (int c8 = 0; c8 < 32; ++c8) {
                const float* wp = Wo + (size_t)t*256 + c8*8;
                float4 w0 = *(const float4*)wp, w1 = *(const float4*)(wp + 4);
                #pragma unroll
                for (int s = 0; s < S_SEC; ++s) {
                    if ((updm >> s) & 1u) {
                        const float4 c0 = *(const float4*)(ctxp + s*256 + c8*8);
                        const float4 c1 = *(const float4*)(ctxp + s*256 + c8*8 + 4);
                        macc[s] += w0.x*c0.x + w0.y*c0.y + w0.z*c0.z + w0.w*c0.w
                                 + w1.x*c1.x + w1.y*c1.y + w1.z*c1.z + w1.w*c1.w;
                    }
                }
            }
            #pragma unroll
            for (int s = 0; s < S_SEC; ++s)
                if ((updm >> s) & 1u) redp[s*256 + t] = fbf(macc[s]);
        }
    }
    __syncthreads();

    // ---- gram margin loss ----
    if (t < S_SEC) {
        float ss = 0.f;
        for (int c8 = 0; c8 < 32; ++c8) {
            float rf[8]; unp8(*(const uint4*)(redp + t*256 + c8*8), rf);
            #pragma unroll
            for (int e = 0; e < 8; ++e) ss += rf[e]*rf[e];
        }
        sInv[t] = 1.f / fmaxf(sqrtf(ss), 1e-8f);
    }
    __syncthreads();
    {
        float contrib = 0.f;
        if (t < 253) {
            int i = 0, rem = t, cnt = 22;
            while (rem >= cnt) { rem -= cnt; --cnt; ++i; }
            const int j = i + 1 + rem;
            float dp = 0.f;
            for (int c8 = 0; c8 < 32; ++c8) {
                float fa[8], fb[8];
                unp8(*(const uint4*)(redp + i*256 + c8*8), fa);
                unp8(*(const uint4*)(redp + j*256 + c8*8), fb);
                #pragma unroll
                for (int e = 0; e < 8; ++e) dp += fa[e]*fb[e];
            }
            const float g = dp * sInv[i] * sInv[j];
            const float c = fabsf(g) - 0.1f;
            contrib = (c > 0.f) ? 2.f*c : 0.f;      // (i,j) and (j,i)
        }
        #pragma unroll
        for (int m = 32; m; m >>= 1) contrib += __shfl_xor(contrib, m);
        if ((t & 63) == 0) sRsc[t >> 6] = contrib;
        __syncthreads();
        if (t == 0) atomicAdd(lossAcc, sRsc[0] + sRsc[1] + sRsc[2] + sRsc[3]);
    }

    // ---- mean pool + classifier logits (fp32 out) ----
    {
        float pv = 0.f;
        #pragma unroll
        for (int s = 0; s < S_SEC; ++s) pv += bf1(redp[s*256 + t]);
        sPool[t] = pv * (1.f/23.f);
    }
    __syncthreads();
    if (t < 25) {
        float a = bp[t];
        for (int c8 = 0; c8 < 32; ++c8) {
            const float* wp = Wp + (size_t)t*256 + c8*8;
            float4 w0 = *(const float4*)wp, w1 = *(const float4*)(wp + 4);
            const float4 p0 = *(const float4*)(sPool + c8*8);
            const float4 p1 = *(const float4*)(sPool + c8*8 + 4);
            a += w0.x*p0.x + w0.y*p0.y + w0.z*p0.z + w0.w*p0.w
               + w1.x*p1.x + w1.y*p1.y + w1.z*p1.z + w1.w*p1.w;
        }
        out[1 + b*25 + t] = a;
    }
}

__global__ void loss_finalize(const float* __restrict__ lossAcc, float* __restrict__ out)
{
    out[0] = lossAcc[0] * (1.f / 1036288.f);   // B*S*(S-1) = 2048*23*22
}

extern "C" void kernel_launch(void* const* d_in, const int* in_sizes, int n_in,
                              void* d_out, int out_size, void* d_ws, size_t ws_size,
                              hipStream_t stream)
{
    const float* cls     = (const float*)d_in[0];
    const int*   mask    = (const int*)d_in[1];
    const float* missing = (const float*)d_in[2];
    const float* W1 = (const float*)d_in[3];  const float* b1 = (const float*)d_in[4];
    const float* W2 = (const float*)d_in[5];  const float* b2 = (const float*)d_in[6];
    const float* lng = (const float*)d_in[7]; const float* lnb = (const float*)d_in[8];
    const float* Wq = (const float*)d_in[9];  const float* bq = (const float*)d_in[10];
    const float* Wk = (const float*)d_in[11]; const float* bk = (const float*)d_in[12];
    const float* Wv = (const float*)d_in[13]; const float* bv = (const float*)d_in[14];
    const float* Wo = (const float*)d_in[15]; const float* bo = (const float*)d_in[16];
    const float* Wp = (const float*)d_in[17]; const float* bp = (const float*)d_in[18];
    float* out = (float*)d_out;
    float* lossAcc = (float*)d_ws;                 // 4 bytes of ws used

    hipMemsetAsync(lossAcc, 0, sizeof(float), stream);
    mega_kernel<<<2048, 256, 0, stream>>>(cls, mask, missing, W1, b1, W2, b2,
                                          lng, lnb, Wq, bq, Wk, bk, Wv, bv,
                                          Wo, bo, Wp, bp, out, lossAcc);
    loss_finalize<<<1, 1, 0, stream>>>(lossAcc, out);
}

// Round 6
// 717.279 us; speedup vs baseline: 4.8068x; 4.8068x over previous
//
#include <hip/hip_runtime.h>

typedef unsigned short u16;
typedef unsigned int u32;
typedef __attribute__((ext_vector_type(8))) short short8;   // 8 bf16 (4 VGPRs)
typedef __attribute__((ext_vector_type(4))) float f32x4;

struct __align__(8) us4 { u16 x, y, z, w; };

__device__ __forceinline__ float bf1(u16 v){ return __uint_as_float(((u32)v) << 16); }
__device__ __forceinline__ float bflo(u32 u){ return __uint_as_float(u << 16); }
__device__ __forceinline__ float bfhi(u32 u){ return __uint_as_float(u & 0xFFFF0000u); }
__device__ __forceinline__ u16 fbf(float f){
    u32 u = __float_as_uint(f);
    return (u16)((u + 0x7FFFu + ((u >> 16) & 1u)) >> 16);   // RTNE
}
__device__ __forceinline__ float gelu_exact(float x){
    return 0.5f * x * (1.0f + erff(x * 0.70710678118654752f));
}
__device__ __forceinline__ void unp8(uint4 u, float* f){
    f[0]=bflo(u.x); f[1]=bfhi(u.x); f[2]=bflo(u.y); f[3]=bfhi(u.y);
    f[4]=bflo(u.z); f[5]=bfhi(u.z); f[6]=bflo(u.w); f[7]=bfhi(u.w);
}
__device__ __forceinline__ uint4 pack8(float4 a, float4 b){
    uint4 u;
    u.x = (u32)fbf(a.x) | ((u32)fbf(a.y) << 16);
    u.y = (u32)fbf(a.z) | ((u32)fbf(a.w) << 16);
    u.z = (u32)fbf(b.x) | ((u32)fbf(b.y) << 16);
    u.w = (u32)fbf(b.z) | ((u32)fbf(b.w) << 16);
    return u;
}

// ---------------------------------------------------------------------------
// ws layout (bytes) — total 61,616,644 (was 134.0 MB in R5; suspected OOB):
//  0          : h1b  [47104x384] bf16  (36,175,872)
//  36175872   : redb [47104x256] bf16  (24,117,248)
//  60293120   : Wb   bf16 weights, wconv order (661,760 elems = 1,323,520 B)
//  61616640   : lossAcc (f32)
// ---------------------------------------------------------------------------

// ---- fp32 -> bf16 weight conversion (7 segments, contiguous dst) ----
__global__ __launch_bounds__(256) void wconv(
    const float* __restrict__ W1, const float* __restrict__ W2,
    const float* __restrict__ Wq, const float* __restrict__ Wk,
    const float* __restrict__ Wv, const float* __restrict__ Wo,
    const float* __restrict__ Wp, u16* __restrict__ dst)
{
    const int i = blockIdx.x * 256 + threadIdx.x;   // grid sized exactly: 661760
    const float* s; int o;
    if      (i < 294912) { s = W1; o = i; }
    else if (i < 393216) { s = W2; o = i - 294912; }
    else if (i < 458752) { s = Wq; o = i - 393216; }
    else if (i < 524288) { s = Wk; o = i - 458752; }
    else if (i < 589824) { s = Wv; o = i - 524288; }
    else if (i < 655360) { s = Wo; o = i - 589824; }
    else                 { s = Wp; o = i - 655360; }
    dst[i] = fbf(s[o]);
}

// ---------------------------------------------------------------------------
// GEMM1 (fused gather): C[N,384] bf16 = gelu(sec @ W1^T + b1),
// sec row n = mask[n]>0 ? cls[n] : missing[n%23], fp32 read -> bf16 staged.
// 128x128 tile, BK=32, 4 waves 2x2, 4x4 MFMA tiles/wave, LDS stride 40.
// ---------------------------------------------------------------------------
__global__ __launch_bounds__(256) void gemm1_kernel(
    const float* __restrict__ cls, const int* __restrict__ mask,
    const float* __restrict__ missing, const u16* __restrict__ W,
    const float* __restrict__ bias, u16* __restrict__ C)
{
    const int K = 768, M = 384;
    __shared__ u16 As[128 * 40];
    __shared__ u16 Bs[128 * 40];
    const int tid = threadIdx.x;
    const int w = tid >> 6, lane = tid & 63;
    const int nBase = blockIdx.y * 128, mBase = blockIdx.x * 128;
    const int wr = w >> 1, wc = w & 1;
    const int r0 = tid >> 2;
    const int co = (tid & 3) * 8;
    const int frow = lane & 15, quad = lane >> 4;

    const int rowA0 = nBase + r0, rowA1 = nBase + r0 + 64;
    const float* ap0 = (mask[rowA0] > 0) ? cls + (size_t)rowA0 * 768
                                         : missing + (size_t)(rowA0 % 23) * 768;
    const float* ap1 = (mask[rowA1] > 0) ? cls + (size_t)rowA1 * 768
                                         : missing + (size_t)(rowA1 % 23) * 768;
    const u16* bp0 = W + (size_t)(mBase + r0) * K;
    const u16* bp1 = W + (size_t)(mBase + r0 + 64) * K;

    f32x4 acc[4][4];
#pragma unroll
    for (int mt = 0; mt < 4; ++mt)
#pragma unroll
        for (int nt = 0; nt < 4; ++nt) acc[mt][nt] = f32x4{0.f, 0.f, 0.f, 0.f};

    float4 a0a = *(const float4*)(ap0 + co), a0b = *(const float4*)(ap0 + co + 4);
    float4 a1a = *(const float4*)(ap1 + co), a1b = *(const float4*)(ap1 + co + 4);
    uint4 pb0 = *(const uint4*)(bp0 + co), pb1 = *(const uint4*)(bp1 + co);

    for (int k0 = 0; k0 < K; k0 += 32) {
        __syncthreads();                 // frags of prev iter consumed
        *(uint4*)(As + r0 * 40 + co) = pack8(a0a, a0b);
        *(uint4*)(As + (r0 + 64) * 40 + co) = pack8(a1a, a1b);
        *(uint4*)(Bs + r0 * 40 + co) = pb0;
        *(uint4*)(Bs + (r0 + 64) * 40 + co) = pb1;
        __syncthreads();
        if (k0 + 32 < K) {
            const int kn = k0 + 32 + co;
            a0a = *(const float4*)(ap0 + kn); a0b = *(const float4*)(ap0 + kn + 4);
            a1a = *(const float4*)(ap1 + kn); a1b = *(const float4*)(ap1 + kn + 4);
            pb0 = *(const uint4*)(bp0 + kn);  pb1 = *(const uint4*)(bp1 + kn);
        }
        short8 af[4], bfv[4];
#pragma unroll
        for (int mt = 0; mt < 4; ++mt)
            af[mt] = *(const short8*)(As + (wr * 64 + mt * 16 + frow) * 40 + quad * 8);
#pragma unroll
        for (int nt = 0; nt < 4; ++nt)
            bfv[nt] = *(const short8*)(Bs + (wc * 64 + nt * 16 + frow) * 40 + quad * 8);
#pragma unroll
        for (int mt = 0; mt < 4; ++mt)
#pragma unroll
            for (int nt = 0; nt < 4; ++nt)
                acc[mt][nt] = __builtin_amdgcn_mfma_f32_16x16x32_bf16(
                    af[mt], bfv[nt], acc[mt][nt], 0, 0, 0);
    }

#pragma unroll
    for (int nt = 0; nt < 4; ++nt) {
        const int col = mBase + wc * 64 + nt * 16 + frow;
        const float bv = bias[col];
#pragma unroll
        for (int mt = 0; mt < 4; ++mt)
#pragma unroll
            for (int reg = 0; reg < 4; ++reg) {
                const int row = nBase + wr * 64 + mt * 16 + quad * 4 + reg;
                C[(size_t)row * M + col] = fbf(gelu_exact(acc[mt][nt][reg] + bv));
            }
    }
}

// ---------------------------------------------------------------------------
// GEMM2 (unchanged R5 gemm_bt): C[N,M] bf16 = gelu(A @ W^T + bias), bf16 in.
// ---------------------------------------------------------------------------
__global__ __launch_bounds__(256) void gemm_bt(
    const u16* __restrict__ A, const u16* __restrict__ W,
    const float* __restrict__ bias, u16* __restrict__ C, int K, int M)
{
    __shared__ u16 As[128 * 40];
    __shared__ u16 Bs[128 * 40];
    const int tid = threadIdx.x;
    const int w = tid >> 6, lane = tid & 63;
    const int nBase = blockIdx.y * 128, mBase = blockIdx.x * 128;
    const int wr = w >> 1, wc = w & 1;
    const int r0 = tid >> 2;
    const int co = (tid & 3) * 8;
    const int frow = lane & 15, quad = lane >> 4;

    f32x4 acc[4][4];
#pragma unroll
    for (int mt = 0; mt < 4; ++mt)
#pragma unroll
        for (int nt = 0; nt < 4; ++nt) acc[mt][nt] = f32x4{0.f, 0.f, 0.f, 0.f};

    uint4 pa0 = *(const uint4*)(A + (size_t)(nBase + r0) * K + co);
    uint4 pa1 = *(const uint4*)(A + (size_t)(nBase + r0 + 64) * K + co);
    uint4 pb0 = *(const uint4*)(W + (size_t)(mBase + r0) * K + co);
    uint4 pb1 = *(const uint4*)(W + (size_t)(mBase + r0 + 64) * K + co);

    for (int k0 = 0; k0 < K; k0 += 32) {
        __syncthreads();
        *(uint4*)(As + r0 * 40 + co) = pa0;
        *(uint4*)(As + (r0 + 64) * 40 + co) = pa1;
        *(uint4*)(Bs + r0 * 40 + co) = pb0;
        *(uint4*)(Bs + (r0 + 64) * 40 + co) = pb1;
        __syncthreads();
        if (k0 + 32 < K) {
            const int kn = k0 + 32 + co;
            pa0 = *(const uint4*)(A + (size_t)(nBase + r0) * K + kn);
            pa1 = *(const uint4*)(A + (size_t)(nBase + r0 + 64) * K + kn);
            pb0 = *(const uint4*)(W + (size_t)(mBase + r0) * K + kn);
            pb1 = *(const uint4*)(W + (size_t)(mBase + r0 + 64) * K + kn);
        }
        short8 af[4], bfv[4];
#pragma unroll
        for (int mt = 0; mt < 4; ++mt)
            af[mt] = *(const short8*)(As + (wr * 64 + mt * 16 + frow) * 40 + quad * 8);
#pragma unroll
        for (int nt = 0; nt < 4; ++nt)
            bfv[nt] = *(const short8*)(Bs + (wc * 64 + nt * 16 + frow) * 40 + quad * 8);
#pragma unroll
        for (int mt = 0; mt < 4; ++mt)
#pragma unroll
            for (int nt = 0; nt < 4; ++nt)
                acc[mt][nt] = __builtin_amdgcn_mfma_f32_16x16x32_bf16(
                    af[mt], bfv[nt], acc[mt][nt], 0, 0, 0);
    }

#pragma unroll
    for (int nt = 0; nt < 4; ++nt) {
        const int col = mBase + wc * 64 + nt * 16 + frow;
        const float bv = bias[col];
#pragma unroll
        for (int mt = 0; mt < 4; ++mt)
#pragma unroll
            for (int reg = 0; reg < 4; ++reg) {
                const int row = nBase + wr * 64 + mt * 16 + quad * 4 + reg;
                C[(size_t)row * M + col] = fbf(gelu_exact(acc[mt][nt][reg] + bv));
            }
    }
}

// ---- LayerNorm over 256, in-place bf16, 1 wave per row ----
__global__ __launch_bounds__(256) void ln_kernel(
    u16* __restrict__ X, const float* __restrict__ g, const float* __restrict__ b)
{
    const int w = threadIdx.x >> 6, lane = threadIdx.x & 63;
    const size_t row = (size_t)blockIdx.x * 4 + w;
    u16* xp = X + row * 256 + lane * 4;
    us4 uv = *(const us4*)xp;
    float x0 = bf1(uv.x), x1 = bf1(uv.y), x2 = bf1(uv.z), x3 = bf1(uv.w);
    float s = x0 + x1 + x2 + x3;
#pragma unroll
    for (int m = 32; m; m >>= 1) s += __shfl_xor(s, m);
    const float mu = s * (1.f / 256.f);
    const float d0 = x0 - mu, d1 = x1 - mu, d2 = x2 - mu, d3 = x3 - mu;
    float vs = d0 * d0 + d1 * d1 + d2 * d2 + d3 * d3;
#pragma unroll
    for (int m = 32; m; m >>= 1) vs += __shfl_xor(vs, m);
    const float rs = rsqrtf(vs * (1.f / 256.f) + 1e-5f);
    const float4 gv = *(const float4*)(g + lane * 4);
    const float4 bv = *(const float4*)(b + lane * 4);
    us4 o;
    o.x = fbf(d0 * rs * gv.x + bv.x);
    o.y = fbf(d1 * rs * gv.y + bv.y);
    o.z = fbf(d2 * rs * gv.z + bv.z);
    o.w = fbf(d3 * rs * gv.w + bv.w);
    *(us4*)xp = o;
}

// ---------------------------------------------------------------------------
// Fused per-EHR tail: QKV (MFMA from LDS red) + softmax/ctx (VALU) +
// Wo (MFMA) + scatter + gram loss + pool + logits. LDS ~66 KB -> 2 blocks/CU.
// ---------------------------------------------------------------------------
#define QSTR 264
__global__ __launch_bounds__(256) void attn_kernel(
    const u16* __restrict__ redg, const int* __restrict__ mask,
    const u16* __restrict__ Wqkvb,                       // [768][256]: q,k,v stacked
    const float* __restrict__ bq, const float* __restrict__ bk,
    const float* __restrict__ bv, const u16* __restrict__ Wob,
    const float* __restrict__ bo, const u16* __restrict__ Wpb,
    const float* __restrict__ bp, float* __restrict__ out,
    float* __restrict__ lossAcc)
{
    __shared__ __align__(16) unsigned char SM[65136];
    u16*   s_red = (u16*)SM;                 // [23][264] red -> "updated"
    u16*   s_q   = (u16*)(SM + 12144);       // [23][264]
    u16*   s_k   = (u16*)(SM + 24288);       // [23][264] -> ctx later
    u16*   s_v   = (u16*)(SM + 36432);       // [23][256]
    float* s_p   = (float*)(SM + 48208);     // [8][23][23] probs (16928 B)
    __shared__ int   sEx[23];
    __shared__ int   sMiss[23];
    __shared__ float sInv[23];
    __shared__ float sPool[256];
    __shared__ float sRsc[4];

    const int b = blockIdx.x, t = threadIdx.x;
    const int w = t >> 6, lane = t & 63;
    const int frow = lane & 15, quad = lane >> 4;
    const int r0c = frow;
    const int r1c = (16 + frow > 22) ? 22 : 16 + frow;   // clamp dup rows

    if (t < 23) sEx[t] = mask[b * 23 + t];
    __syncthreads();
    if (t == 0) {
        int any = 0;
        for (int s = 0; s < 23; ++s) any |= (sEx[s] > 0) ? 1 : 0;
        for (int s = 0; s < 23; ++s) sMiss[s] = (any && sEx[s] <= 0) ? 1 : 0;
    }
    // stage red
    for (int i = t; i < 736; i += 256) {
        const int s = i >> 5, c8 = (i & 31) * 8;
        *(uint4*)(s_red + s * QSTR + c8) =
            *(const uint4*)(redg + ((size_t)(b * 23 + s)) * 256 + c8);
    }
    __syncthreads();

    // ---- QKV via MFMA: D[s][n] = red[s][:] . Wqkv[n][:], n in [w*192, w*192+192) ----
    {
        f32x4 qacc[2][12];
#pragma unroll
        for (int mt = 0; mt < 2; ++mt)
#pragma unroll
            for (int nt = 0; nt < 12; ++nt) qacc[mt][nt] = f32x4{0.f, 0.f, 0.f, 0.f};
        for (int k0 = 0; k0 < 256; k0 += 32) {
            short8 a0 = *(const short8*)(s_red + r0c * QSTR + k0 + quad * 8);
            short8 a1 = *(const short8*)(s_red + r1c * QSTR + k0 + quad * 8);
#pragma unroll
            for (int nt = 0; nt < 12; ++nt) {
                const int n = w * 192 + nt * 16 + frow;
                short8 bfr = *(const short8*)(Wqkvb + (size_t)n * 256 + k0 + quad * 8);
                qacc[0][nt] = __builtin_amdgcn_mfma_f32_16x16x32_bf16(a0, bfr, qacc[0][nt], 0, 0, 0);
                qacc[1][nt] = __builtin_amdgcn_mfma_f32_16x16x32_bf16(a1, bfr, qacc[1][nt], 0, 0, 0);
            }
        }
#pragma unroll
        for (int mt = 0; mt < 2; ++mt)
#pragma unroll
            for (int nt = 0; nt < 12; ++nt) {
                const int col = w * 192 + nt * 16 + frow;
                const int seg = col >> 8, cm = col & 255;
                const float bb = (seg == 0) ? bq[cm] : (seg == 1) ? bk[cm] : bv[cm];
#pragma unroll
                for (int reg = 0; reg < 4; ++reg) {
                    const int s = mt * 16 + quad * 4 + reg;
                    if (s < 23) {
                        const u16 hv = fbf(qacc[mt][nt][reg] + bb);
                        if (seg == 0)      s_q[s * QSTR + cm] = hv;
                        else if (seg == 1) s_k[s * QSTR + cm] = hv;
                        else               s_v[s * 256 + cm] = hv;
                    }
                }
            }
    }
    __syncthreads();

    // ---- scores + masked softmax -> s_p (184 threads: 8 heads x 23 queries) ----
    if (t < 184) {
        const int hh = t / 23, qi = t - hh * 23;
        const u16* qrow = s_q + qi * QSTR + hh * 32;
        float qf[32];
#pragma unroll
        for (int c8 = 0; c8 < 4; ++c8) unp8(*(const uint4*)(qrow + c8 * 8), qf + c8 * 8);
        float p[23];
        float mx = -1e30f;
#pragma unroll
        for (int j = 0; j < 23; ++j) {
            const u16* krow = s_k + j * QSTR + hh * 32;
            float sc = 0.f;
#pragma unroll
            for (int c8 = 0; c8 < 4; ++c8) {
                float kf[8]; unp8(*(const uint4*)(krow + c8 * 8), kf);
#pragma unroll
                for (int e = 0; e < 8; ++e) sc += qf[c8 * 8 + e] * kf[e];
            }
            sc *= 0.17677669529663687f;      // 1/sqrt(32)
            if (sEx[j] <= 0) sc = -1e9f;
            p[j] = sc; mx = fmaxf(mx, sc);
        }
        float sum = 0.f;
#pragma unroll
        for (int j = 0; j < 23; ++j) { p[j] = expf(p[j] - mx); sum += p[j]; }
        const float inv = 1.f / sum;
#pragma unroll
        for (int j = 0; j < 23; ++j) s_p[(hh * 23 + qi) * 23 + j] = p[j] * inv;
    }
    __syncthreads();                          // q,k reads done; s_p ready

    // ---- ctx (into s_k region): thread t owns column d=t, head h=t>>5 ----
    {
        const int d = t, h = t >> 5;
        float vreg[23];
#pragma unroll
        for (int j = 0; j < 23; ++j) vreg[j] = bf1(s_v[j * 256 + d]);
#pragma unroll
        for (int s = 0; s < 23; ++s) {
            float a = 0.f;
#pragma unroll
            for (int j = 0; j < 23; ++j) a += s_p[(h * 23 + s) * 23 + j] * vreg[j];
            s_k[s * QSTR + d] = fbf(a);
        }
    }
    __syncthreads();

    // ---- Wo via MFMA: upd[s][n] = ctx[s][:] . Wo[n][:], scatter missing rows ----
    {
        f32x4 wacc[2][4];
#pragma unroll
        for (int mt = 0; mt < 2; ++mt)
#pragma unroll
            for (int nt = 0; nt < 4; ++nt) wacc[mt][nt] = f32x4{0.f, 0.f, 0.f, 0.f};
        for (int k0 = 0; k0 < 256; k0 += 32) {
            short8 a0 = *(const short8*)(s_k + r0c * QSTR + k0 + quad * 8);
            short8 a1 = *(const short8*)(s_k + r1c * QSTR + k0 + quad * 8);
#pragma unroll
            for (int nt = 0; nt < 4; ++nt) {
                const int n = w * 64 + nt * 16 + frow;
                short8 bfr = *(const short8*)(Wob + (size_t)n * 256 + k0 + quad * 8);
                wacc[0][nt] = __builtin_amdgcn_mfma_f32_16x16x32_bf16(a0, bfr, wacc[0][nt], 0, 0, 0);
                wacc[1][nt] = __builtin_amdgcn_mfma_f32_16x16x32_bf16(a1, bfr, wacc[1][nt], 0, 0, 0);
            }
        }
#pragma unroll
        for (int mt = 0; mt < 2; ++mt)
#pragma unroll
            for (int nt = 0; nt < 4; ++nt) {
                const int col = w * 64 + nt * 16 + frow;
                const float bvv = bo[col];
#pragma unroll
                for (int reg = 0; reg < 4; ++reg) {
                    const int s = mt * 16 + quad * 4 + reg;
                    if (s < 23 && sMiss[s])
                        s_red[s * QSTR + col] = fbf(wacc[mt][nt][reg] + bvv);
                }
            }
    }
    __syncthreads();

    // ---- row norms ----
    if (t < 23) {
        float ss = 0.f;
        for (int c8 = 0; c8 < 32; ++c8) {
            float rf[8]; unp8(*(const uint4*)(s_red + t * QSTR + c8 * 8), rf);
#pragma unroll
            for (int e = 0; e < 8; ++e) ss += rf[e] * rf[e];
        }
        sInv[t] = 1.f / fmaxf(sqrtf(ss), 1e-8f);
    }
    __syncthreads();
    // ---- gram margin loss (253 pairs) ----
    {
        float contrib = 0.f;
        if (t < 253) {
            int i = 0, rem = t, cnt = 22;
            while (rem >= cnt) { rem -= cnt; --cnt; ++i; }
            const int j = i + 1 + rem;
            float dp = 0.f;
            for (int c8 = 0; c8 < 32; ++c8) {
                float fa[8], fb[8];
                unp8(*(const uint4*)(s_red + i * QSTR + c8 * 8), fa);
                unp8(*(const uint4*)(s_red + j * QSTR + c8 * 8), fb);
#pragma unroll
                for (int e = 0; e < 8; ++e) dp += fa[e] * fb[e];
            }
            const float g = dp * sInv[i] * sInv[j];
            const float c = fabsf(g) - 0.1f;
            contrib = (c > 0.f) ? 2.f * c : 0.f;    // (i,j) and (j,i)
        }
#pragma unroll
        for (int m = 32; m; m >>= 1) contrib += __shfl_xor(contrib, m);
        if (lane == 0) sRsc[w] = contrib;
        __syncthreads();
        if (t == 0) atomicAdd(lossAcc, sRsc[0] + sRsc[1] + sRsc[2] + sRsc[3]);
    }
    // ---- mean pool + logits ----
    {
        float pv = 0.f;
#pragma unroll
        for (int s = 0; s < 23; ++s) pv += bf1(s_red[s * QSTR + t]);
        sPool[t] = pv * (1.f / 23.f);
    }
    __syncthreads();
    if (t < 25) {
        float a = bp[t];
        for (int c8 = 0; c8 < 32; ++c8) {
            float wf[8]; unp8(*(const uint4*)(Wpb + (size_t)t * 256 + c8 * 8), wf);
            const float4 p0 = *(const float4*)(sPool + c8 * 8);
            const float4 p1 = *(const float4*)(sPool + c8 * 8 + 4);
            a += wf[0] * p0.x + wf[1] * p0.y + wf[2] * p0.z + wf[3] * p0.w
               + wf[4] * p1.x + wf[5] * p1.y + wf[6] * p1.z + wf[7] * p1.w;
        }
        out[1 + b * 25 + t] = a;
    }
}

__global__ void loss_finalize(const float* __restrict__ lossAcc, float* __restrict__ out)
{
    out[0] = lossAcc[0] * (1.f / 1036288.f);   // B*S*(S-1) = 2048*23*22
}

// ---------------------------------------------------------------------------
extern "C" void kernel_launch(void* const* d_in, const int* in_sizes, int n_in,
                              void* d_out, int out_size, void* d_ws, size_t ws_size,
                              hipStream_t stream)
{
    const float* cls     = (const float*)d_in[0];
    const int*   mask    = (const int*)d_in[1];
    const float* missing = (const float*)d_in[2];
    const float* W1 = (const float*)d_in[3];  const float* b1 = (const float*)d_in[4];
    const float* W2 = (const float*)d_in[5];  const float* b2 = (const float*)d_in[6];
    const float* lng = (const float*)d_in[7]; const float* lnb = (const float*)d_in[8];
    const float* Wq = (const float*)d_in[9];  const float* bq = (const float*)d_in[10];
    const float* Wk = (const float*)d_in[11]; const float* bk = (const float*)d_in[12];
    const float* Wv = (const float*)d_in[13]; const float* bv = (const float*)d_in[14];
    const float* Wo = (const float*)d_in[15]; const float* bo = (const float*)d_in[16];
    const float* Wp = (const float*)d_in[17]; const float* bp = (const float*)d_in[18];
    float* out = (float*)d_out;

    char* ws = (char*)d_ws;
    u16* h1b  = (u16*)ws;                         // [47104x384]
    u16* redb = (u16*)(ws + 36175872);            // [47104x256]
    u16* Wb   = (u16*)(ws + 60293120);            // bf16 weights (661,760 elems)
    u16* W1b   = Wb;
    u16* W2b   = Wb + 294912;
    u16* Wqkvb = Wb + 393216;                     // q,k,v contiguous [768][256]
    u16* Wob   = Wb + 589824;
    u16* Wpb   = Wb + 655360;
    float* lossAcc = (float*)(ws + 61616640);

    hipMemsetAsync(lossAcc, 0, sizeof(float), stream);

    wconv<<<2585, 256, 0, stream>>>(W1, W2, Wq, Wk, Wv, Wo, Wp, Wb);
    // h1 = gelu(gather(cls,missing,mask) @ W1^T + b1)
    gemm1_kernel<<<dim3(3, 368), 256, 0, stream>>>(cls, mask, missing, W1b, b1, h1b);
    // h2 = gelu(h1 @ W2^T + b2) -> redb (pre-LN)
    gemm_bt<<<dim3(2, 368), 256, 0, stream>>>(h1b, W2b, b2, redb, 384, 256);
    // red = LN(h2) in-place
    ln_kernel<<<11776, 256, 0, stream>>>(redb, lng, lnb);
    // QKV + attention + scatter + loss + pool + logits
    attn_kernel<<<2048, 256, 0, stream>>>(redb, mask, Wqkvb, bq, bk, bv,
                                          Wob, bo, Wpb, bp, out, lossAcc);
    loss_finalize<<<1, 1, 0, stream>>>(lossAcc, out);
}

// Round 7
// 607.584 us; speedup vs baseline: 5.6746x; 1.1805x over previous
//
#include <hip/hip_runtime.h>

typedef unsigned short u16;
typedef unsigned int u32;
typedef __attribute__((ext_vector_type(8))) short short8;   // 8 bf16 (4 VGPRs)
typedef __attribute__((ext_vector_type(4))) float f32x4;

struct __align__(8) us4 { u16 x, y, z, w; };

__device__ __forceinline__ float bf1(u16 v){ return __uint_as_float(((u32)v) << 16); }
__device__ __forceinline__ float bflo(u32 u){ return __uint_as_float(u << 16); }
__device__ __forceinline__ float bfhi(u32 u){ return __uint_as_float(u & 0xFFFF0000u); }
__device__ __forceinline__ u16 fbf(float f){
    u32 u = __float_as_uint(f);
    return (u16)((u + 0x7FFFu + ((u >> 16) & 1u)) >> 16);   // RTNE
}
__device__ __forceinline__ float gelu_exact(float x){
    return 0.5f * x * (1.0f + erff(x * 0.70710678118654752f));
}
__device__ __forceinline__ void unp8(uint4 u, float* f){
    f[0]=bflo(u.x); f[1]=bfhi(u.x); f[2]=bflo(u.y); f[3]=bfhi(u.y);
    f[4]=bflo(u.z); f[5]=bfhi(u.z); f[6]=bflo(u.w); f[7]=bfhi(u.w);
}
__device__ __forceinline__ uint4 pack8(float4 a, float4 b){
    uint4 u;
    u.x = (u32)fbf(a.x) | ((u32)fbf(a.y) << 16);
    u.y = (u32)fbf(a.z) | ((u32)fbf(a.w) << 16);
    u.z = (u32)fbf(b.x) | ((u32)fbf(b.y) << 16);
    u.w = (u32)fbf(b.z) | ((u32)fbf(b.w) << 16);
    return u;
}

// ---------------------------------------------------------------------------
// ws layout (bytes) — total 61,616,644 (R6-proven size):
//  0          : h1b  [47104x384] bf16  (36,175,872)
//  36175872   : redb [47104x256] bf16  (24,117,248)  red -> "updated" in place
//  60293120   : Wb   bf16 weights, wconv order (661,760 elems = 1,323,520 B)
//  61616640   : lossAcc (f32)
// ---------------------------------------------------------------------------

__global__ __launch_bounds__(256) void wconv(
    const float* __restrict__ W1, const float* __restrict__ W2,
    const float* __restrict__ Wq, const float* __restrict__ Wk,
    const float* __restrict__ Wv, const float* __restrict__ Wo,
    const float* __restrict__ Wp, u16* __restrict__ dst)
{
    const int i = blockIdx.x * 256 + threadIdx.x;   // grid exactly 661760
    const float* s; int o;
    if      (i < 294912) { s = W1; o = i; }
    else if (i < 393216) { s = W2; o = i - 294912; }
    else if (i < 458752) { s = Wq; o = i - 393216; }
    else if (i < 524288) { s = Wk; o = i - 458752; }
    else if (i < 589824) { s = Wv; o = i - 524288; }
    else if (i < 655360) { s = Wo; o = i - 589824; }
    else                 { s = Wp; o = i - 655360; }
    dst[i] = fbf(s[o]);
}

// ---------------------------------------------------------------------------
// GEMM1 (fused gather): C[N,384] bf16 = gelu(sec @ W1^T + b1).
// ---------------------------------------------------------------------------
__global__ __launch_bounds__(256) void gemm1_kernel(
    const float* __restrict__ cls, const int* __restrict__ mask,
    const float* __restrict__ missing, const u16* __restrict__ W,
    const float* __restrict__ bias, u16* __restrict__ C)
{
    const int K = 768, M = 384;
    __shared__ u16 As[128 * 40];
    __shared__ u16 Bs[128 * 40];
    const int tid = threadIdx.x;
    const int w = tid >> 6, lane = tid & 63;
    const int nBase = blockIdx.y * 128, mBase = blockIdx.x * 128;
    const int wr = w >> 1, wc = w & 1;
    const int r0 = tid >> 2;
    const int co = (tid & 3) * 8;
    const int frow = lane & 15, quad = lane >> 4;

    const int rowA0 = nBase + r0, rowA1 = nBase + r0 + 64;
    const float* ap0 = (mask[rowA0] > 0) ? cls + (size_t)rowA0 * 768
                                         : missing + (size_t)(rowA0 % 23) * 768;
    const float* ap1 = (mask[rowA1] > 0) ? cls + (size_t)rowA1 * 768
                                         : missing + (size_t)(rowA1 % 23) * 768;
    const u16* bp0 = W + (size_t)(mBase + r0) * K;
    const u16* bp1 = W + (size_t)(mBase + r0 + 64) * K;

    f32x4 acc[4][4];
#pragma unroll
    for (int mt = 0; mt < 4; ++mt)
#pragma unroll
        for (int nt = 0; nt < 4; ++nt) acc[mt][nt] = f32x4{0.f, 0.f, 0.f, 0.f};

    float4 a0a = *(const float4*)(ap0 + co), a0b = *(const float4*)(ap0 + co + 4);
    float4 a1a = *(const float4*)(ap1 + co), a1b = *(const float4*)(ap1 + co + 4);
    uint4 pb0 = *(const uint4*)(bp0 + co), pb1 = *(const uint4*)(bp1 + co);

    for (int k0 = 0; k0 < K; k0 += 32) {
        __syncthreads();
        *(uint4*)(As + r0 * 40 + co) = pack8(a0a, a0b);
        *(uint4*)(As + (r0 + 64) * 40 + co) = pack8(a1a, a1b);
        *(uint4*)(Bs + r0 * 40 + co) = pb0;
        *(uint4*)(Bs + (r0 + 64) * 40 + co) = pb1;
        __syncthreads();
        if (k0 + 32 < K) {
            const int kn = k0 + 32 + co;
            a0a = *(const float4*)(ap0 + kn); a0b = *(const float4*)(ap0 + kn + 4);
            a1a = *(const float4*)(ap1 + kn); a1b = *(const float4*)(ap1 + kn + 4);
            pb0 = *(const uint4*)(bp0 + kn);  pb1 = *(const uint4*)(bp1 + kn);
        }
        short8 af[4], bfv[4];
#pragma unroll
        for (int mt = 0; mt < 4; ++mt)
            af[mt] = *(const short8*)(As + (wr * 64 + mt * 16 + frow) * 40 + quad * 8);
#pragma unroll
        for (int nt = 0; nt < 4; ++nt)
            bfv[nt] = *(const short8*)(Bs + (wc * 64 + nt * 16 + frow) * 40 + quad * 8);
#pragma unroll
        for (int mt = 0; mt < 4; ++mt)
#pragma unroll
            for (int nt = 0; nt < 4; ++nt)
                acc[mt][nt] = __builtin_amdgcn_mfma_f32_16x16x32_bf16(
                    af[mt], bfv[nt], acc[mt][nt], 0, 0, 0);
    }

#pragma unroll
    for (int nt = 0; nt < 4; ++nt) {
        const int col = mBase + wc * 64 + nt * 16 + frow;
        const float bv = bias[col];
#pragma unroll
        for (int mt = 0; mt < 4; ++mt)
#pragma unroll
            for (int reg = 0; reg < 4; ++reg) {
                const int row = nBase + wr * 64 + mt * 16 + quad * 4 + reg;
                C[(size_t)row * M + col] = fbf(gelu_exact(acc[mt][nt][reg] + bv));
            }
    }
}

// ---------------------------------------------------------------------------
// GEMM2: C[N,M] bf16 = gelu(A @ W^T + bias), bf16 inputs.
// ---------------------------------------------------------------------------
__global__ __launch_bounds__(256) void gemm_bt(
    const u16* __restrict__ A, const u16* __restrict__ W,
    const float* __restrict__ bias, u16* __restrict__ C, int K, int M)
{
    __shared__ u16 As[128 * 40];
    __shared__ u16 Bs[128 * 40];
    const int tid = threadIdx.x;
    const int w = tid >> 6, lane = tid & 63;
    const int nBase = blockIdx.y * 128, mBase = blockIdx.x * 128;
    const int wr = w >> 1, wc = w & 1;
    const int r0 = tid >> 2;
    const int co = (tid & 3) * 8;
    const int frow = lane & 15, quad = lane >> 4;

    f32x4 acc[4][4];
#pragma unroll
    for (int mt = 0; mt < 4; ++mt)
#pragma unroll
        for (int nt = 0; nt < 4; ++nt) acc[mt][nt] = f32x4{0.f, 0.f, 0.f, 0.f};

    uint4 pa0 = *(const uint4*)(A + (size_t)(nBase + r0) * K + co);
    uint4 pa1 = *(const uint4*)(A + (size_t)(nBase + r0 + 64) * K + co);
    uint4 pb0 = *(const uint4*)(W + (size_t)(mBase + r0) * K + co);
    uint4 pb1 = *(const uint4*)(W + (size_t)(mBase + r0 + 64) * K + co);

    for (int k0 = 0; k0 < K; k0 += 32) {
        __syncthreads();
        *(uint4*)(As + r0 * 40 + co) = pa0;
        *(uint4*)(As + (r0 + 64) * 40 + co) = pa1;
        *(uint4*)(Bs + r0 * 40 + co) = pb0;
        *(uint4*)(Bs + (r0 + 64) * 40 + co) = pb1;
        __syncthreads();
        if (k0 + 32 < K) {
            const int kn = k0 + 32 + co;
            pa0 = *(const uint4*)(A + (size_t)(nBase + r0) * K + kn);
            pa1 = *(const uint4*)(A + (size_t)(nBase + r0 + 64) * K + kn);
            pb0 = *(const uint4*)(W + (size_t)(mBase + r0) * K + kn);
            pb1 = *(const uint4*)(W + (size_t)(mBase + r0 + 64) * K + kn);
        }
        short8 af[4], bfv[4];
#pragma unroll
        for (int mt = 0; mt < 4; ++mt)
            af[mt] = *(const short8*)(As + (wr * 64 + mt * 16 + frow) * 40 + quad * 8);
#pragma unroll
        for (int nt = 0; nt < 4; ++nt)
            bfv[nt] = *(const short8*)(Bs + (wc * 64 + nt * 16 + frow) * 40 + quad * 8);
#pragma unroll
        for (int mt = 0; mt < 4; ++mt)
#pragma unroll
            for (int nt = 0; nt < 4; ++nt)
                acc[mt][nt] = __builtin_amdgcn_mfma_f32_16x16x32_bf16(
                    af[mt], bfv[nt], acc[mt][nt], 0, 0, 0);
    }

#pragma unroll
    for (int nt = 0; nt < 4; ++nt) {
        const int col = mBase + wc * 64 + nt * 16 + frow;
        const float bv = bias[col];
#pragma unroll
        for (int mt = 0; mt < 4; ++mt)
#pragma unroll
            for (int reg = 0; reg < 4; ++reg) {
                const int row = nBase + wr * 64 + mt * 16 + quad * 4 + reg;
                C[(size_t)row * M + col] = fbf(gelu_exact(acc[mt][nt][reg] + bv));
            }
    }
}

// ---- LayerNorm over 256, in-place bf16, 1 wave per row ----
__global__ __launch_bounds__(256) void ln_kernel(
    u16* __restrict__ X, const float* __restrict__ g, const float* __restrict__ b)
{
    const int w = threadIdx.x >> 6, lane = threadIdx.x & 63;
    const size_t row = (size_t)blockIdx.x * 4 + w;
    u16* xp = X + row * 256 + lane * 4;
    us4 uv = *(const us4*)xp;
    float x0 = bf1(uv.x), x1 = bf1(uv.y), x2 = bf1(uv.z), x3 = bf1(uv.w);
    float s = x0 + x1 + x2 + x3;
#pragma unroll
    for (int m = 32; m; m >>= 1) s += __shfl_xor(s, m);
    const float mu = s * (1.f / 256.f);
    const float d0 = x0 - mu, d1 = x1 - mu, d2 = x2 - mu, d3 = x3 - mu;
    float vs = d0 * d0 + d1 * d1 + d2 * d2 + d3 * d3;
#pragma unroll
    for (int m = 32; m; m >>= 1) vs += __shfl_xor(vs, m);
    const float rs = rsqrtf(vs * (1.f / 256.f) + 1e-5f);
    const float4 gv = *(const float4*)(g + lane * 4);
    const float4 bv = *(const float4*)(b + lane * 4);
    us4 o;
    o.x = fbf(d0 * rs * gv.x + bv.x);
    o.y = fbf(d1 * rs * gv.y + bv.y);
    o.z = fbf(d2 * rs * gv.z + bv.z);
    o.w = fbf(d3 * rs * gv.w + bv.w);
    *(us4*)xp = o;
}

// ---------------------------------------------------------------------------
// attn1 per batch element: QKV (MFMA) + softmax + ctx + Wo (MFMA) + scatter
// of missing rows into global redb (in place). LDS 44.9 KB -> 3 blocks/CU.
// ---------------------------------------------------------------------------
#define QSTR 264
__global__ __launch_bounds__(256) void attn1_kernel(
    u16* __restrict__ redb, const int* __restrict__ mask,
    const u16* __restrict__ Wqkvb,                       // [768][256]: q,k,v stacked
    const float* __restrict__ bq, const float* __restrict__ bk,
    const float* __restrict__ bv, const u16* __restrict__ Wob,
    const float* __restrict__ bo)
{
    __shared__ __align__(16) unsigned char SM[44896];
    u16* s_rq = (u16*)SM;                  // [23][264] red (A for QKV) -> q after barrier
    u16* s_k  = (u16*)(SM + 12144);        // [23][264] k -> ctx later
    u16* s_v  = (u16*)(SM + 24288);        // [23][256]
    u16* s_p  = (u16*)(SM + 36064);        // bf16 probs [8][23][24] = 8832 B
    __shared__ int sEx[23];
    __shared__ int sMiss[23];

    const int b = blockIdx.x, t = threadIdx.x;
    const int w = t >> 6, lane = t & 63;
    const int frow = lane & 15, quad = lane >> 4;
    const int r0c = frow;
    const int r1c = (16 + frow > 22) ? 22 : 16 + frow;   // clamp dup rows

    if (t < 23) sEx[t] = mask[b * 23 + t];
    __syncthreads();
    if (t == 0) {
        int any = 0;
        for (int s = 0; s < 23; ++s) any |= (sEx[s] > 0) ? 1 : 0;
        for (int s = 0; s < 23; ++s) sMiss[s] = (any && sEx[s] <= 0) ? 1 : 0;
    }
    // stage red
    for (int i = t; i < 736; i += 256) {
        const int s = i >> 5, c8 = (i & 31) * 8;
        *(uint4*)(s_rq + s * QSTR + c8) =
            *(const uint4*)(redb + ((size_t)(b * 23 + s)) * 256 + c8);
    }
    __syncthreads();

    // ---- QKV via MFMA: D[s][n] = red[s][:] . Wqkv[n][:], n in [w*192,(w+1)*192) ----
    {
        f32x4 qacc[2][12];
#pragma unroll
        for (int mt = 0; mt < 2; ++mt)
#pragma unroll
            for (int nt = 0; nt < 12; ++nt) qacc[mt][nt] = f32x4{0.f, 0.f, 0.f, 0.f};
        for (int k0 = 0; k0 < 256; k0 += 32) {
            short8 a0 = *(const short8*)(s_rq + r0c * QSTR + k0 + quad * 8);
            short8 a1 = *(const short8*)(s_rq + r1c * QSTR + k0 + quad * 8);
#pragma unroll
            for (int nt = 0; nt < 12; ++nt) {
                const int n = w * 192 + nt * 16 + frow;
                short8 bfr = *(const short8*)(Wqkvb + (size_t)n * 256 + k0 + quad * 8);
                qacc[0][nt] = __builtin_amdgcn_mfma_f32_16x16x32_bf16(a0, bfr, qacc[0][nt], 0, 0, 0);
                qacc[1][nt] = __builtin_amdgcn_mfma_f32_16x16x32_bf16(a1, bfr, qacc[1][nt], 0, 0, 0);
            }
        }
        __syncthreads();           // all A-reads of red done -> q may overlay
#pragma unroll
        for (int mt = 0; mt < 2; ++mt)
#pragma unroll
            for (int nt = 0; nt < 12; ++nt) {
                const int col = w * 192 + nt * 16 + frow;
                const int seg = col >> 8, cm = col & 255;
                const float bb = (seg == 0) ? bq[cm] : (seg == 1) ? bk[cm] : bv[cm];
#pragma unroll
                for (int reg = 0; reg < 4; ++reg) {
                    const int s = mt * 16 + quad * 4 + reg;
                    if (s < 23) {
                        const u16 hv = fbf(qacc[mt][nt][reg] + bb);
                        if (seg == 0)      s_rq[s * QSTR + cm] = hv;   // q (red dead)
                        else if (seg == 1) s_k[s * QSTR + cm] = hv;
                        else               s_v[s * 256 + cm] = hv;
                    }
                }
            }
    }
    __syncthreads();

    // ---- scores + masked softmax -> s_p bf16 (184 threads: 8 h x 23 q) ----
    if (t < 184) {
        const int hh = t / 23, qi = t - hh * 23;
        const u16* qrow = s_rq + qi * QSTR + hh * 32;
        float qf[32];
#pragma unroll
        for (int c8 = 0; c8 < 4; ++c8) unp8(*(const uint4*)(qrow + c8 * 8), qf + c8 * 8);
        float p[23];
        float mx = -1e30f;
#pragma unroll
        for (int j = 0; j < 23; ++j) {
            const u16* krow = s_k + j * QSTR + hh * 32;
            float sc = 0.f;
#pragma unroll
            for (int c8 = 0; c8 < 4; ++c8) {
                float kf[8]; unp8(*(const uint4*)(krow + c8 * 8), kf);
#pragma unroll
                for (int e = 0; e < 8; ++e) sc += qf[c8 * 8 + e] * kf[e];
            }
            sc *= 0.17677669529663687f;      // 1/sqrt(32)
            if (sEx[j] <= 0) sc = -1e9f;
            p[j] = sc; mx = fmaxf(mx, sc);
        }
        float sum = 0.f;
#pragma unroll
        for (int j = 0; j < 23; ++j) { p[j] = expf(p[j] - mx); sum += p[j]; }
        const float inv = 1.f / sum;
#pragma unroll
        for (int j = 0; j < 23; ++j) s_p[(hh * 23 + qi) * 24 + j] = fbf(p[j] * inv);
    }
    __syncthreads();                          // q,k reads done; s_p ready

    // ---- ctx (into s_k): thread t owns column d=t, head h=t>>5 ----
    {
        const int d = t, h = t >> 5;
        float vreg[23];
#pragma unroll
        for (int j = 0; j < 23; ++j) vreg[j] = bf1(s_v[j * 256 + d]);
#pragma unroll
        for (int s = 0; s < 23; ++s) {
            float a = 0.f;
            const u16* pr = s_p + (h * 23 + s) * 24;
#pragma unroll
            for (int j = 0; j < 23; ++j) a += bf1(pr[j]) * vreg[j];
            s_k[s * QSTR + d] = fbf(a);
        }
    }
    __syncthreads();

    // ---- Wo via MFMA: upd[s][n] = ctx[s][:] . Wo[n][:], scatter to global ----
    {
        f32x4 wacc[2][4];
#pragma unroll
        for (int mt = 0; mt < 2; ++mt)
#pragma unroll
            for (int nt = 0; nt < 4; ++nt) wacc[mt][nt] = f32x4{0.f, 0.f, 0.f, 0.f};
        for (int k0 = 0; k0 < 256; k0 += 32) {
            short8 a0 = *(const short8*)(s_k + r0c * QSTR + k0 + quad * 8);
            short8 a1 = *(const short8*)(s_k + r1c * QSTR + k0 + quad * 8);
#pragma unroll
            for (int nt = 0; nt < 4; ++nt) {
                const int n = w * 64 + nt * 16 + frow;
                short8 bfr = *(const short8*)(Wob + (size_t)n * 256 + k0 + quad * 8);
                wacc[0][nt] = __builtin_amdgcn_mfma_f32_16x16x32_bf16(a0, bfr, wacc[0][nt], 0, 0, 0);
                wacc[1][nt] = __builtin_amdgcn_mfma_f32_16x16x32_bf16(a1, bfr, wacc[1][nt], 0, 0, 0);
            }
        }
#pragma unroll
        for (int mt = 0; mt < 2; ++mt)
#pragma unroll
            for (int nt = 0; nt < 4; ++nt) {
                const int col = w * 64 + nt * 16 + frow;
                const float bvv = bo[col];
#pragma unroll
                for (int reg = 0; reg < 4; ++reg) {
                    const int s = mt * 16 + quad * 4 + reg;
                    if (s < 23 && sMiss[s])
                        redb[((size_t)(b * 23 + s)) * 256 + col] =
                            fbf(wacc[mt][nt][reg] + bvv);
                }
            }
    }
}

// ---------------------------------------------------------------------------
// tail per batch element: norms + gram margin loss + pool + logits.
// LDS ~13.5 KB -> wave-limited 8 blocks/CU.
// ---------------------------------------------------------------------------
__global__ __launch_bounds__(256) void tail_kernel(
    const u16* __restrict__ redb, const u16* __restrict__ Wpb,
    const float* __restrict__ bp, float* __restrict__ out,
    float* __restrict__ lossAcc)
{
    __shared__ __align__(16) u16 s_u[23 * QSTR];
    __shared__ float sInv[23];
    __shared__ float sPool[256];
    __shared__ float sRsc[4];

    const int b = blockIdx.x, t = threadIdx.x;
    const int w = t >> 6, lane = t & 63;

    for (int i = t; i < 736; i += 256) {
        const int s = i >> 5, c8 = (i & 31) * 8;
        *(uint4*)(s_u + s * QSTR + c8) =
            *(const uint4*)(redb + ((size_t)(b * 23 + s)) * 256 + c8);
    }
    __syncthreads();

    if (t < 23) {
        float ss = 0.f;
        for (int c8 = 0; c8 < 32; ++c8) {
            float rf[8]; unp8(*(const uint4*)(s_u + t * QSTR + c8 * 8), rf);
#pragma unroll
            for (int e = 0; e < 8; ++e) ss += rf[e] * rf[e];
        }
        sInv[t] = 1.f / fmaxf(sqrtf(ss), 1e-8f);
    }
    __syncthreads();

    {
        float contrib = 0.f;
        if (t < 253) {
            int i = 0, rem = t, cnt = 22;
            while (rem >= cnt) { rem -= cnt; --cnt; ++i; }
            const int j = i + 1 + rem;
            float dp = 0.f;
            for (int c8 = 0; c8 < 32; ++c8) {
                float fa[8], fb[8];
                unp8(*(const uint4*)(s_u + i * QSTR + c8 * 8), fa);
                unp8(*(const uint4*)(s_u + j * QSTR + c8 * 8), fb);
#pragma unroll
                for (int e = 0; e < 8; ++e) dp += fa[e] * fb[e];
            }
            const float g = dp * sInv[i] * sInv[j];
            const float c = fabsf(g) - 0.1f;
            contrib = (c > 0.f) ? 2.f * c : 0.f;    // (i,j) and (j,i)
        }
#pragma unroll
        for (int m = 32; m; m >>= 1) contrib += __shfl_xor(contrib, m);
        if (lane == 0) sRsc[w] = contrib;
        __syncthreads();
        if (t == 0) atomicAdd(lossAcc, sRsc[0] + sRsc[1] + sRsc[2] + sRsc[3]);
    }

    {
        float pv = 0.f;
#pragma unroll
        for (int s = 0; s < 23; ++s) pv += bf1(s_u[s * QSTR + t]);
        sPool[t] = pv * (1.f / 23.f);
    }
    __syncthreads();
    if (t < 25) {
        float a = bp[t];
        for (int c8 = 0; c8 < 32; ++c8) {
            float wf[8]; unp8(*(const uint4*)(Wpb + (size_t)t * 256 + c8 * 8), wf);
            const float4 p0 = *(const float4*)(sPool + c8 * 8);
            const float4 p1 = *(const float4*)(sPool + c8 * 8 + 4);
            a += wf[0] * p0.x + wf[1] * p0.y + wf[2] * p0.z + wf[3] * p0.w
               + wf[4] * p1.x + wf[5] * p1.y + wf[6] * p1.z + wf[7] * p1.w;
        }
        out[1 + b * 25 + t] = a;
    }
}

__global__ void loss_finalize(const float* __restrict__ lossAcc, float* __restrict__ out)
{
    out[0] = lossAcc[0] * (1.f / 1036288.f);   // B*S*(S-1) = 2048*23*22
}

// ---------------------------------------------------------------------------
extern "C" void kernel_launch(void* const* d_in, const int* in_sizes, int n_in,
                              void* d_out, int out_size, void* d_ws, size_t ws_size,
                              hipStream_t stream)
{
    const float* cls     = (const float*)d_in[0];
    const int*   mask    = (const int*)d_in[1];
    const float* missing = (const float*)d_in[2];
    const float* W1 = (const float*)d_in[3];  const float* b1 = (const float*)d_in[4];
    const float* W2 = (const float*)d_in[5];  const float* b2 = (const float*)d_in[6];
    const float* lng = (const float*)d_in[7]; const float* lnb = (const float*)d_in[8];
    const float* Wq = (const float*)d_in[9];  const float* bq = (const float*)d_in[10];
    const float* Wk = (const float*)d_in[11]; const float* bk = (const float*)d_in[12];
    const float* Wv = (const float*)d_in[13]; const float* bv = (const float*)d_in[14];
    const float* Wo = (const float*)d_in[15]; const float* bo = (const float*)d_in[16];
    const float* Wp = (const float*)d_in[17]; const float* bp = (const float*)d_in[18];
    float* out = (float*)d_out;

    char* ws = (char*)d_ws;
    u16* h1b  = (u16*)ws;                         // [47104x384]
    u16* redb = (u16*)(ws + 36175872);            // [47104x256] red -> updated
    u16* Wb   = (u16*)(ws + 60293120);            // bf16 weights (661,760 elems)
    u16* W1b   = Wb;
    u16* W2b   = Wb + 294912;
    u16* Wqkvb = Wb + 393216;                     // q,k,v contiguous [768][256]
    u16* Wob   = Wb + 589824;
    u16* Wpb   = Wb + 655360;
    float* lossAcc = (float*)(ws + 61616640);

    hipMemsetAsync(lossAcc, 0, sizeof(float), stream);

    wconv<<<2585, 256, 0, stream>>>(W1, W2, Wq, Wk, Wv, Wo, Wp, Wb);
    // h1 = gelu(gather(cls,missing,mask) @ W1^T + b1)
    gemm1_kernel<<<dim3(3, 368), 256, 0, stream>>>(cls, mask, missing, W1b, b1, h1b);
    // h2 = gelu(h1 @ W2^T + b2) -> redb (pre-LN)
    gemm_bt<<<dim3(2, 368), 256, 0, stream>>>(h1b, W2b, b2, redb, 384, 256);
    // red = LN(h2) in-place
    ln_kernel<<<11776, 256, 0, stream>>>(redb, lng, lnb);
    // QKV + attention + Wo, scatter missing rows into redb (becomes "updated")
    attn1_kernel<<<2048, 256, 0, stream>>>(redb, mask, Wqkvb, bq, bk, bv, Wob, bo);
    // norms + gram loss + pool + logits
    tail_kernel<<<2048, 256, 0, stream>>>(redb, Wpb, bp, out, lossAcc);
    loss_finalize<<<1, 1, 0, stream>>>(lossAcc, out);
}